// Round 6
// baseline (254.327 us; speedup 1.0000x reference)
//
#include <hip/hip_runtime.h>
#include <hip/hip_bf16.h>
#include <cstdint>
#include <cstddef>

#define BB   4
#define SS   2048
#define HIDD 1024
#define NHH  16
#define HDD  64
#define MM   (BB*SS)   // 8192
#define L2E  1.4426950408889634f
#define SH4  5.770780163555854f   // 4 * L2E

typedef __bf16    bf16x8 __attribute__((ext_vector_type(8)));
typedef float     f32x4  __attribute__((ext_vector_type(4)));
typedef _Float16  half4  __attribute__((ext_vector_type(4)));
typedef _Float16  half8  __attribute__((ext_vector_type(8)));
typedef _Float16  half2v __attribute__((ext_vector_type(2)));
typedef unsigned  u32x4  __attribute__((ext_vector_type(4)));

__device__ __forceinline__ unsigned short f2b(float f) {
    unsigned u = __builtin_bit_cast(unsigned, f);
    return (unsigned short)((u + 0x7FFFu + ((u >> 16) & 1u)) >> 16);
}

__device__ __forceinline__ half2v pkrtz(float a, float b) {
    return __builtin_bit_cast(half2v, __builtin_amdgcn_cvt_pkrtz(a, b));
}

__device__ __forceinline__ unsigned pkrtz_u(float a, float b) {
    return __builtin_bit_cast(unsigned, __builtin_amdgcn_cvt_pkrtz(a, b));
}

// async global->LDS, 16B per lane. LDS dest must be wave-uniform base + lane*16.
__device__ __forceinline__ void gl_lds16(const void* g, void* l) {
    __builtin_amdgcn_global_load_lds(
        (const __attribute__((address_space(1))) void*)g,
        (__attribute__((address_space(3))) void*)l, 16, 0, 0);
}

// ---------------------------------------------------------------- fp32 -> bf16 (all 4 srcs)
#define NX4 (MM * HIDD / 4)
#define NW4 (HIDD * HIDD / 4)   // 262144 = 2^18
__global__ __launch_bounds__(256) void cvt_all(
    const float* __restrict__ x,  const float* __restrict__ wq,
    const float* __restrict__ wk, const float* __restrict__ wv,
    unsigned short* __restrict__ xb, unsigned short* __restrict__ wb)
{
    int i = blockIdx.x * 256 + threadIdx.x;
    const float* src; unsigned short* dst; int off;
    if (i < NX4) { src = x; dst = xb; off = i; }
    else {
        int j = i - NX4;
        int w = j >> 18;          // 0,1,2
        off = j & (NW4 - 1);
        src = (w == 0) ? wq : (w == 1) ? wk : wv;
        dst = wb + (size_t)w * HIDD * HIDD;
    }
    float4 v = reinterpret_cast<const float4*>(src)[off];
    ushort4 o;
    o.x = f2b(v.x); o.y = f2b(v.y); o.z = f2b(v.z); o.w = f2b(v.w);
    reinterpret_cast<ushort4*>(dst)[off] = o;
}

// ---------------------------------------------------------------- QKV GEMM (R6: phase schedule)
// C = x @ W^T + b. BM=256, BN=128, BK=64; 512 threads = 8 waves (4m x 2n), each
// owning a 64x64 output (acc[4][4], identical fragment/epilogue math to the
// proven 128^2 kernel - only offA/offB ranges and m0 scale changed).
// grid (32 m-tiles [fastest -> XCD = id%8 = x%8, so all 24 (op,n) blocks of an
// m-tile share one XCD's L2], 24 = op*8 + n-tile). 768 blocks = 3 full rounds.
// SCHEDULE (T3+T4, m201 cadence): 3-deep LDS buffers (144 KB, 1 block/CU);
// tile t's loads issued during tile t-2; per tile 2 phases of
//   {issue 3 gl_lds(t+2) | 8 ds_read_b128 | s_barrier | setprio1 16 MFMA setprio0 | s_barrier}
// and ONE s_waitcnt vmcnt(6) per tile (outstanding = t+1's 6 + t+2's 6; waiting
// 6 drains exactly t+1; t=14 -> vmcnt(0); never 0 in steady state). Raw
// s_barrier (not __syncthreads) so the compiler's forced vmcnt(0)-before-barrier
// drain is gone; sched_barrier(0) before each barrier pins LDS-op motion.
// Race audit: read buf = t%3, write buf = (t+2)%3 (disjoint); stage into buf b
// happens one full tile-barrier after the last ds_read of b; vmcnt before the
// barrier makes per-thread load completion block-global.
__global__ __launch_bounds__(512, 1) void qkv_gemm(
    const unsigned short* __restrict__ xb,
    const unsigned short* __restrict__ wb,
    const float* __restrict__ bq, const float* __restrict__ bk, const float* __restrict__ bv,
    unsigned short* __restrict__ Qb, unsigned short* __restrict__ Kb,
    _Float16* __restrict__ Vtb)
{
    __shared__ unsigned short lA[3][256 * 64];  // x-tile, 32 KB each
    __shared__ unsigned short lB[3][128 * 64];  // W-tile, 16 KB each

    const int tid  = threadIdx.x;
    const int wave = tid >> 6, lane = tid & 63;
    const int lh   = lane & 15, quad = lane >> 4;
    const int l7   = lh & 7;
    const int m0   = blockIdx.x * 256;
    const int opn  = blockIdx.y;
    const int op   = opn >> 3;            // 0=Q 1=K 2=V
    const int n0   = (opn & 7) * 128;
    const unsigned short* W = wb + (size_t)op * HIDD * HIDD;
    const float* bias = (op == 0) ? bq : (op == 1) ? bk : bv;

    f32x4 acc[4][4];
#pragma unroll
    for (int i = 0; i < 4; i++)
#pragma unroll
        for (int j = 0; j < 4; j++) acc[i][j] = f32x4{0.f, 0.f, 0.f, 0.f};

    const int wm = wave & 3;              // m-quadrant 0..3 (64 rows each)
    const int wn = wave >> 2;             // n-half     0..1 (64 cols each)
    // A-operand rows: op<2 -> W (n-dim), op==2 -> x (m-dim). Same as 128^2 kernel.
    const int offA = (op == 2) ? wm : wn;
    const int offB = (op == 2) ? wn : wm;

    const int srow = tid >> 3;            // 0..63
    const int sg   = tid & 7;             // 16B group 0..7

// stage half H (0/1) of K-tile T into buffer BUF: 2 A-rows + 1 B-row per thread
#define STG(T, BUF, H) do {                                                          \
    const int k0_ = (T) * 64;                                                        \
    const int rA0 = srow + ((H) ? 128 : 0);                                          \
    const int rA1 = rA0 + 64;                                                        \
    const int rB  = srow + ((H) ? 64 : 0);                                           \
    gl_lds16(&xb[(size_t)(m0 + rA0) * HIDD + k0_ + ((sg ^ (rA0 & 7)) << 3)],         \
             &lA[BUF][rA0 * 64 + sg * 8]);                                           \
    gl_lds16(&xb[(size_t)(m0 + rA1) * HIDD + k0_ + ((sg ^ (rA1 & 7)) << 3)],         \
             &lA[BUF][rA1 * 64 + sg * 8]);                                           \
    gl_lds16(&W [(size_t)(n0 + rB ) * HIDD + k0_ + ((sg ^ (rB  & 7)) << 3)],         \
             &lB[BUF][rB * 64 + sg * 8]);                                            \
} while (0)

    // prologue: tiles 0,1 fully staged; wait own tile-0 loads (12 out -> 6), rendezvous
    STG(0, 0, 0); STG(0, 0, 1);
    STG(1, 1, 0); STG(1, 1, 1);
    asm volatile("s_waitcnt vmcnt(6)" ::: "memory");
    __builtin_amdgcn_s_barrier();

    for (int t = 0; t < 16; ++t) {
        const int buf  = t % 3;
        const int nbuf = (t + 2) % 3;
        const unsigned short* sA = (op == 2) ? lA[buf] : lB[buf];
        const unsigned short* sB = (op == 2) ? lB[buf] : lA[buf];

#pragma unroll
        for (int kk = 0; kk < 2; ++kk) {
            if (t + 2 < 16) STG(t + 2, nbuf, kk);
            bf16x8 aF[4], bF[4];
#pragma unroll
            for (int i = 0; i < 4; i++)
                aF[i] = *reinterpret_cast<const bf16x8*>(
                    &sA[(offA * 64 + i * 16 + lh) * 64 + (((kk * 4 + quad) ^ l7) << 3)]);
#pragma unroll
            for (int j = 0; j < 4; j++)
                bF[j] = *reinterpret_cast<const bf16x8*>(
                    &sB[(offB * 64 + j * 16 + lh) * 64 + (((kk * 4 + quad) ^ l7) << 3)]);
            __builtin_amdgcn_sched_barrier(0);
            __builtin_amdgcn_s_barrier();
            __builtin_amdgcn_s_setprio(1);
#pragma unroll
            for (int i = 0; i < 4; i++)
#pragma unroll
                for (int j = 0; j < 4; j++)
                    acc[i][j] = __builtin_amdgcn_mfma_f32_16x16x32_bf16(aF[i], bF[j], acc[i][j], 0, 0, 0);
            __builtin_amdgcn_s_setprio(0);
            if (kk == 0) {
                __builtin_amdgcn_sched_barrier(0);
                __builtin_amdgcn_s_barrier();
            }
        }
        // tile boundary: ensure tile t+1's loads are globally complete.
        if (t < 15) {
            __builtin_amdgcn_sched_barrier(0);
            if (t < 14) asm volatile("s_waitcnt vmcnt(6)" ::: "memory");
            else        asm volatile("s_waitcnt vmcnt(0)" ::: "memory");
            __builtin_amdgcn_s_barrier();
        }
    }
#undef STG

    // epilogue: C/D layout col = lane&15, row = quad*4 + reg (verbatim from 128^2 kernel)
    if (op == 2) {
        // rows = m (s), cols = n (d): V^T[d][s], 4 consecutive s per lane -> half4
#pragma unroll
        for (int j = 0; j < 4; j++) {
            const int n = n0 + offB * 64 + j * 16 + lh;
            const float bvv = bias[n];
            const int h = n >> 6, d = n & 63;
#pragma unroll
            for (int i = 0; i < 4; i++) {
                const int mrow = m0 + offA * 64 + i * 16 + quad * 4;
                const int b_ = mrow >> 11, s_ = mrow & 2047;
                half2v h01 = pkrtz(acc[i][j][0] + bvv, acc[i][j][1] + bvv);
                half2v h23 = pkrtz(acc[i][j][2] + bvv, acc[i][j][3] + bvv);
                half4 hv; hv[0] = h01[0]; hv[1] = h01[1]; hv[2] = h23[0]; hv[3] = h23[1];
                size_t a = ((size_t)(b_ * NHH + h) * HDD + d) * SS + s_;
                *reinterpret_cast<half4*>(&Vtb[a]) = hv;
            }
        }
    } else {
        // rows = n (d), cols = m (s): Q/K[s][d], 4 consecutive d per lane -> ushort4
        const float qs = (op == 0) ? (0.125f * L2E) : 1.0f;
        unsigned short* dst = (op == 0) ? Qb : Kb;
#pragma unroll
        for (int i = 0; i < 4; i++) {
            const int nb = n0 + offA * 64 + i * 16 + quad * 4;
            const float4 bb = *reinterpret_cast<const float4*>(&bias[nb]);
            const int h = nb >> 6, d = nb & 63;
#pragma unroll
            for (int j = 0; j < 4; j++) {
                const int m = m0 + offB * 64 + j * 16 + lh;
                const int b_ = m >> 11, s_ = m & 2047;
                ushort4 o;
                o.x = f2b((acc[i][j][0] + bb.x) * qs);
                o.y = f2b((acc[i][j][1] + bb.y) * qs);
                o.z = f2b((acc[i][j][2] + bb.z) * qs);
                o.w = f2b((acc[i][j][3] + bb.w) * qs);
                *reinterpret_cast<ushort4*>(
                    &dst[((size_t)(b_ * NHH + h) * SS + s_) * HDD + d]) = o;
            }
        }
    }
}

// ---------------------------------------------------------------- flash attention
// (R4 version, best measured 76.9 us - reverted from R5's q-tile-256 experiment.)
// grid (64 = b*NH+h, 16 q-tiles). 256 threads, q-tile 128 (32 q per wave),
// kt tile 64 keys, double-buffered. S^T = K*Q^T with PERMUTED key rows: the QK
// C-output concatenated over a=0/1 is exactly the K=32 16x16x32 f16 PV B-operand.
// Half-tile PV carry across the per-kt barrier fills the post-barrier LDS ramp.
__global__ __launch_bounds__(256, 4) void attn_kernel(
    const unsigned short* __restrict__ Qb,
    const unsigned short* __restrict__ Kb,
    const _Float16* __restrict__ Vtb,
    const float* __restrict__ mask,
    float* __restrict__ out)
{
    __shared__ unsigned short lK[2][64 * 64];  // keys x d, swizzled (bits 0,1,3); 8 KB each
    __shared__ _Float16      lV[2][64 * 64];   // d x keys, swizzled (bits 0,1,2); 8 KB each
    __shared__ float         lmm[SS];          // mask*L2E - SH4, per key; 8 KB

    const int tid  = threadIdx.x;
    const int wave = tid >> 6, lane = tid & 63;
    const int lh   = lane & 15, quad = lane >> 4;
    const int l7   = lh & 7;
    const int bh = blockIdx.x, qt = blockIdx.y;
    const int b = bh >> 4, h = bh & 15;
    const unsigned short* Qh = Qb  + (size_t)bh * SS * HDD;
    const unsigned short* Kh = Kb  + (size_t)bh * SS * HDD;
    const _Float16*       Vh = Vtb + (size_t)bh * HDD * SS;
    const float* mk = mask + (size_t)b * SS;
    const int q0 = qt * 128;

    // Q fragments (B-operand): q = q0 + wave*32 + i*16 + lh, d = kk*32 + quad*8
    bf16x8 qF[2][2];
#pragma unroll
    for (int i = 0; i < 2; i++)
#pragma unroll
        for (int kk = 0; kk < 2; kk++)
            qF[i][kk] = *reinterpret_cast<const bf16x8*>(
                &Qh[(size_t)(q0 + wave * 32 + i * 16 + lh) * HDD + kk * 32 + quad * 8]);

    f32x4 oacc[2][4];
#pragma unroll
    for (int i = 0; i < 2; i++)
#pragma unroll
        for (int dj = 0; dj < 4; dj++) oacc[i][dj] = f32x4{0.f, 0.f, 0.f, 0.f};
    f32x4 osum[2] = {f32x4{0.f, 0.f, 0.f, 0.f}, f32x4{0.f, 0.f, 0.f, 0.f}};

    const u32x4 one_u = {0x3C003C00u, 0x3C003C00u, 0x3C003C00u, 0x3C003C00u};
    const half8 vone  = __builtin_bit_cast(half8, one_u);

    const int srow = tid >> 3;        // 0..31
    const int sg   = tid & 7;

#define STAGE(KT, BUF) do {                                                     \
    const int kb_ = (KT) * 64;                                                  \
    _Pragma("unroll")                                                           \
    for (int rr = 0; rr < 2; rr++) {                                            \
        const int row = srow + rr * 32;                                         \
        const int swk = ((sg ^ ((row & 3) | ((row >> 1) & 4))) << 3);           \
        const int swv = ((sg ^ (row & 7)) << 3);                                \
        gl_lds16(&Kh[(size_t)(kb_ + row) * HDD + swk], &lK[BUF][row * 64 + sg * 8]); \
        gl_lds16(&Vh[(size_t)row * SS + kb_ + swv],    &lV[BUF][row * 64 + sg * 8]); \
    }                                                                           \
} while (0)

// QK scores + exp2 + pack for half-tile T (0/1) of tile kt -> PF[2][4] words
#define A_HALF(T, PF) do {                                                     \
    _Pragma("unroll")                                                          \
    for (int a = 0; a < 2; a++) {                                              \
        const int key = (T) * 32 + ((lh & 12) << 1) + (a << 2) + (lh & 3);     \
        const int krow = key * 64;                                             \
        bf16x8 kf0 = *reinterpret_cast<const bf16x8*>(                         \
            &lK[buf][krow + ((quad ^ l7) << 3)]);                              \
        bf16x8 kf1 = *reinterpret_cast<const bf16x8*>(                         \
            &lK[buf][krow + (((4 + quad) ^ l7) << 3)]);                        \
        const f32x4 mm = *reinterpret_cast<const f32x4*>(                      \
            &lmm[kb + (T) * 32 + quad * 8 + a * 4]);                           \
        _Pragma("unroll")                                                      \
        for (int i = 0; i < 2; i++) {                                          \
            f32x4 s = __builtin_amdgcn_mfma_f32_16x16x32_bf16(kf0, qF[i][0], mm, 0, 0, 0); \
            s = __builtin_amdgcn_mfma_f32_16x16x32_bf16(kf1, qF[i][1], s, 0, 0, 0);        \
            PF[i][a * 2 + 0] = pkrtz_u(__builtin_amdgcn_exp2f(s[0]),           \
                                       __builtin_amdgcn_exp2f(s[1]));          \
            PF[i][a * 2 + 1] = pkrtz_u(__builtin_amdgcn_exp2f(s[2]),           \
                                       __builtin_amdgcn_exp2f(s[3]));          \
        }                                                                      \
    }                                                                          \
} while (0)

// V fragment for half-tile T of tile kt (4 conflict-free ds_read_b128)
#define LOADV(T, VF) do {                                                      \
    _Pragma("unroll")                                                          \
    for (int dj = 0; dj < 4; dj++)                                             \
        VF[dj] = *reinterpret_cast<const half8*>(                              \
            &lV[buf][(dj * 16 + lh) * 64 + ((((T) * 4 + quad) ^ l7) << 3)]);   \
} while (0)

// PV + row-sum for one half-tile: 10 pure-register K=32 f16 MFMAs
#define PV_HALF(PF, VF) do {                                                   \
    __builtin_amdgcn_s_setprio(1);                                             \
    _Pragma("unroll")                                                          \
    for (int i = 0; i < 2; i++) {                                              \
        const u32x4 pu = {PF[i][0], PF[i][1], PF[i][2], PF[i][3]};             \
        const half8 pF = __builtin_bit_cast(half8, pu);                        \
        osum[i] = __builtin_amdgcn_mfma_f32_16x16x32_f16(vone, pF, osum[i], 0, 0, 0); \
        _Pragma("unroll")                                                      \
        for (int dj = 0; dj < 4; dj++)                                         \
            oacc[i][dj] = __builtin_amdgcn_mfma_f32_16x16x32_f16(              \
                VF[dj], pF, oacc[i][dj], 0, 0, 0);                             \
    }                                                                          \
    __builtin_amdgcn_s_setprio(0);                                             \
} while (0)

    // carried half-tile state (consumed at top of body, rewritten at bottom)
    unsigned pfc[2][4];
    half8    vfc[4];
#pragma unroll
    for (int i = 0; i < 2; i++)
#pragma unroll
        for (int w = 0; w < 4; w++) pfc[i][w] = 0u;
#pragma unroll
    for (int dj = 0; dj < 4; dj++)
        vfc[dj] = __builtin_bit_cast(half8, u32x4{0u, 0u, 0u, 0u});

    STAGE(0, 0);

    // one-time: mask -> exp2-domain additive term, staged in LDS
#pragma unroll
    for (int j = 0; j < 2; j++) {
        const int idx = tid * 8 + j * 4;
        float4 m = *reinterpret_cast<const float4*>(&mk[idx]);
        float4 r;
        r.x = __builtin_fmaf(m.x, L2E, -SH4);
        r.y = __builtin_fmaf(m.y, L2E, -SH4);
        r.z = __builtin_fmaf(m.z, L2E, -SH4);
        r.w = __builtin_fmaf(m.w, L2E, -SH4);
        *reinterpret_cast<float4*>(&lmm[idx]) = r;
    }
    __syncthreads();

    for (int kt = 0; kt < SS / 64; kt++) {
        if (kt < SS / 64 - 1) STAGE(kt + 1, (kt + 1) & 1);
        const int buf = kt & 1;
        const int kb = kt * 64;

        // PV of the carried half-tile: register-only, fills post-barrier ramp
        PV_HALF(pfc, vfc);

        // half-tile 0 of this kt
        unsigned pf0[2][4];
        A_HALF(0, pf0);
        half8 vf0[4];
        LOADV(0, vf0);
        PV_HALF(pf0, vf0);

        // half-tile 1 -> carry (ds_reads complete before the barrier -> safe
        // vs STAGE(kt+2) overwriting this buffer next iteration)
        A_HALF(1, pfc);
        LOADV(1, vfc);

        if (kt < SS / 64 - 1) __syncthreads();
    }
    PV_HALF(pfc, vfc);   // last carried half-tile (kt=31, t=1)

    // finalize: osum[i][0] already holds the full row sum for q = lh (all lanes)
#pragma unroll
    for (int i = 0; i < 2; i++) {
        const float rls = 1.0f / osum[i][0];
        const int q = q0 + wave * 32 + i * 16 + lh;
#pragma unroll
        for (int dj = 0; dj < 4; dj++) {
            float4 o4;
            o4.x = oacc[i][dj][0] * rls;
            o4.y = oacc[i][dj][1] * rls;
            o4.z = oacc[i][dj][2] * rls;
            o4.w = oacc[i][dj][3] * rls;
            *reinterpret_cast<float4*>(
                &out[((size_t)b * SS + q) * HIDD + h * HDD + dj * 16 + quad * 4]) = o4;
        }
    }
#undef PV_HALF
#undef LOADV
#undef A_HALF
#undef STAGE
}

// ---------------------------------------------------------------- launch
extern "C" void kernel_launch(void* const* d_in, const int* in_sizes, int n_in,
                              void* d_out, int out_size, void* d_ws, size_t ws_size,
                              hipStream_t stream) {
    const float* x    = (const float*)d_in[0];
    const float* mask = (const float*)d_in[1];
    const float* Wq   = (const float*)d_in[2];
    const float* bq   = (const float*)d_in[3];
    const float* Wk   = (const float*)d_in[4];
    const float* bk   = (const float*)d_in[5];
    const float* Wv   = (const float*)d_in[6];
    const float* bv   = (const float*)d_in[7];
    float* out = (float*)d_out;
    (void)in_sizes; (void)n_in; (void)out_size; (void)ws_size;

    unsigned short* ws  = (unsigned short*)d_ws;
    unsigned short* xb  = ws;                                   // 8192*1024
    unsigned short* wb  = xb + (size_t)MM * HIDD;               // 3*1024*1024
    unsigned short* Qb  = wb + (size_t)3 * HIDD * HIDD;         // 8192*1024
    unsigned short* Kb  = Qb + (size_t)MM * HIDD;               // 8192*1024
    _Float16*       Vtb = (_Float16*)(Kb + (size_t)MM * HIDD);  // 8192*1024 f16, transposed

    cvt_all<<<(NX4 + 3 * NW4) / 256, 256, 0, stream>>>(x, Wq, Wk, Wv, xb, wb);

    qkv_gemm<<<dim3(MM / 256, 24), 512, 0, stream>>>(xb, wb, bq, bk, bv, Qb, Kb, Vtb);

    attn_kernel<<<dim3(BB * NHH, SS / 128), 256, 0, stream>>>(Qb, Kb, Vtb, mask, out);
}

// Round 7
// 233.974 us; speedup vs baseline: 1.0870x; 1.0870x over previous
//
#include <hip/hip_runtime.h>
#include <hip/hip_bf16.h>
#include <cstdint>
#include <cstddef>

#define BB   4
#define SS   2048
#define HIDD 1024
#define NHH  16
#define HDD  64
#define MM   (BB*SS)   // 8192
#define L2E  1.4426950408889634f
#define SH4  5.770780163555854f   // 4 * L2E

typedef __bf16    bf16x8 __attribute__((ext_vector_type(8)));
typedef float     f32x4  __attribute__((ext_vector_type(4)));
typedef _Float16  half4  __attribute__((ext_vector_type(4)));
typedef _Float16  half8  __attribute__((ext_vector_type(8)));
typedef _Float16  half2v __attribute__((ext_vector_type(2)));
typedef unsigned  u32x4  __attribute__((ext_vector_type(4)));

__device__ __forceinline__ unsigned short f2b(float f) {
    unsigned u = __builtin_bit_cast(unsigned, f);
    return (unsigned short)((u + 0x7FFFu + ((u >> 16) & 1u)) >> 16);
}

__device__ __forceinline__ half2v pkrtz(float a, float b) {
    return __builtin_bit_cast(half2v, __builtin_amdgcn_cvt_pkrtz(a, b));
}

__device__ __forceinline__ unsigned pkrtz_u(float a, float b) {
    return __builtin_bit_cast(unsigned, __builtin_amdgcn_cvt_pkrtz(a, b));
}

// async global->LDS, 16B per lane. LDS dest must be wave-uniform base + lane*16.
__device__ __forceinline__ void gl_lds16(const void* g, void* l) {
    __builtin_amdgcn_global_load_lds(
        (const __attribute__((address_space(1))) void*)g,
        (__attribute__((address_space(3))) void*)l, 16, 0, 0);
}

// ---------------------------------------------------------------- fp32 -> bf16 (all 4 srcs)
#define NX4 (MM * HIDD / 4)
#define NW4 (HIDD * HIDD / 4)   // 262144 = 2^18
__global__ __launch_bounds__(256) void cvt_all(
    const float* __restrict__ x,  const float* __restrict__ wq,
    const float* __restrict__ wk, const float* __restrict__ wv,
    unsigned short* __restrict__ xb, unsigned short* __restrict__ wb)
{
    int i = blockIdx.x * 256 + threadIdx.x;
    const float* src; unsigned short* dst; int off;
    if (i < NX4) { src = x; dst = xb; off = i; }
    else {
        int j = i - NX4;
        int w = j >> 18;          // 0,1,2
        off = j & (NW4 - 1);
        src = (w == 0) ? wq : (w == 1) ? wk : wv;
        dst = wb + (size_t)w * HIDD * HIDD;
    }
    float4 v = reinterpret_cast<const float4*>(src)[off];
    ushort4 o;
    o.x = f2b(v.x); o.y = f2b(v.y); o.z = f2b(v.z); o.w = f2b(v.w);
    reinterpret_cast<ushort4*>(dst)[off] = o;
}

// ---------------------------------------------------------------- QKV GEMM
// (R7: reverted to the proven 128^2 2-barrier kernel from rounds 0-5. The R6
// 256x128 3-deep phase schedule regressed to 99us / MfmaUtil 20%: 144KB LDS ->
// 1 block/CU in lockstep barriers, no inter-block slide. The 128^2 version runs
// 3-4 independent blocks/CU whose barriers interleave - the m114 implicit
// overlap. ONE controlled change vs R0-R5: launch_bounds(256,4) (was 3) ->
// 4 blocks/CU, 128KB LDS total, VGPR cap 128 (loop needs ~100, low spill risk).
// If qkv shows in top-5 (>77us) next round, that's the spill tripwire: revert to 3.)
// C = x @ W^T + b. grid (64 m-tiles [fastest -> XCD = m%8], 24 = op*8 + n-tile).
// BK=64, XOR-swizzled LDS (row stride 64 elems; 16B group g ^= row&7).
// Operand roles per op:
//   op==2 (V): A = x-tile (rows m), B = W-tile (rows n) -> C rows = s  -> half4 V^T stores
//   op<2 (Q,K): A = W-tile (rows n), B = x-tile (rows m) -> C rows = d -> ushort4 stores
// Q,K written bf16 [B,NH,S,HD]; V written f16 transposed [B,NH,HD,S].
// Q pre-scaled by 0.125*log2(e) (folds softmax scale AND exp->exp2 conversion).
__global__ __launch_bounds__(256, 4) void qkv_gemm(
    const unsigned short* __restrict__ xb,
    const unsigned short* __restrict__ wb,
    const float* __restrict__ bq, const float* __restrict__ bk, const float* __restrict__ bv,
    unsigned short* __restrict__ Qb, unsigned short* __restrict__ Kb,
    _Float16* __restrict__ Vtb)
{
    __shared__ unsigned short lA[128 * 64];  // x-tile, 16 KB
    __shared__ unsigned short lB[128 * 64];  // W-tile, 16 KB

    const int tid  = threadIdx.x;
    const int wave = tid >> 6, lane = tid & 63;
    const int lh   = lane & 15, quad = lane >> 4;
    const int l7   = lh & 7;
    const int m0   = blockIdx.x * 128;
    const int opn  = blockIdx.y;
    const int op   = opn >> 3;            // 0=Q 1=K 2=V
    const int n0   = (opn & 7) * 128;
    const unsigned short* W = wb + (size_t)op * HIDD * HIDD;
    const float* bias = (op == 0) ? bq : (op == 1) ? bk : bv;

    f32x4 acc[4][4];
#pragma unroll
    for (int i = 0; i < 4; i++)
#pragma unroll
        for (int j = 0; j < 4; j++) acc[i][j] = f32x4{0.f, 0.f, 0.f, 0.f};

    const int wm = wave & 1, wn = wave >> 1;
    // A/B operand sources (wave-uniform)
    const unsigned short* srcA = (op == 2) ? lA : lB;
    const unsigned short* srcB = (op == 2) ? lB : lA;
    const int offA = (op == 2) ? wm : wn;
    const int offB = (op == 2) ? wn : wm;

    const int srow = tid >> 3;        // 0..31
    const int sg   = tid & 7;         // 16B group 0..7

    for (int k0 = 0; k0 < HIDD; k0 += 64) {
#pragma unroll
        for (int rr = 0; rr < 4; rr++) {
            const int row = srow + rr * 32;
            const int gcol = k0 + ((sg ^ (row & 7)) << 3);
            gl_lds16(&xb[(size_t)(m0 + row) * HIDD + gcol], &lA[row * 64 + sg * 8]);
            gl_lds16(&W [(size_t)(n0 + row) * HIDD + gcol], &lB[row * 64 + sg * 8]);
        }
        __syncthreads();

#pragma unroll
        for (int kk = 0; kk < 2; kk++) {
            bf16x8 aF[4], bF[4];
#pragma unroll
            for (int i = 0; i < 4; i++) {
                const int row = offA * 64 + i * 16 + lh;
                aF[i] = *reinterpret_cast<const bf16x8*>(
                    &srcA[row * 64 + (((kk * 4 + quad) ^ l7) << 3)]);
            }
#pragma unroll
            for (int j = 0; j < 4; j++) {
                const int row = offB * 64 + j * 16 + lh;
                bF[j] = *reinterpret_cast<const bf16x8*>(
                    &srcB[row * 64 + (((kk * 4 + quad) ^ l7) << 3)]);
            }
#pragma unroll
            for (int i = 0; i < 4; i++)
#pragma unroll
                for (int j = 0; j < 4; j++)
                    acc[i][j] = __builtin_amdgcn_mfma_f32_16x16x32_bf16(aF[i], bF[j], acc[i][j], 0, 0, 0);
        }
        __syncthreads();
    }

    // epilogue: C/D layout col = lane&15, row = quad*4 + reg
    if (op == 2) {
        // rows = m (s), cols = n (d): V^T[d][s], 4 consecutive s per lane -> half4
#pragma unroll
        for (int j = 0; j < 4; j++) {
            const int n = n0 + offB * 64 + j * 16 + lh;
            const float bvv = bias[n];
            const int h = n >> 6, d = n & 63;
#pragma unroll
            for (int i = 0; i < 4; i++) {
                const int mrow = m0 + offA * 64 + i * 16 + quad * 4;
                const int b_ = mrow >> 11, s_ = mrow & 2047;
                half2v h01 = pkrtz(acc[i][j][0] + bvv, acc[i][j][1] + bvv);
                half2v h23 = pkrtz(acc[i][j][2] + bvv, acc[i][j][3] + bvv);
                half4 hv; hv[0] = h01[0]; hv[1] = h01[1]; hv[2] = h23[0]; hv[3] = h23[1];
                size_t a = ((size_t)(b_ * NHH + h) * HDD + d) * SS + s_;
                *reinterpret_cast<half4*>(&Vtb[a]) = hv;
            }
        }
    } else {
        // rows = n (d), cols = m (s): Q/K[s][d], 4 consecutive d per lane -> ushort4
        const float qs = (op == 0) ? (0.125f * L2E) : 1.0f;
        unsigned short* dst = (op == 0) ? Qb : Kb;
#pragma unroll
        for (int i = 0; i < 4; i++) {
            const int nb = n0 + offA * 64 + i * 16 + quad * 4;
            const float4 bb = *reinterpret_cast<const float4*>(&bias[nb]);
            const int h = nb >> 6, d = nb & 63;
#pragma unroll
            for (int j = 0; j < 4; j++) {
                const int m = m0 + offB * 64 + j * 16 + lh;
                const int b_ = m >> 11, s_ = m & 2047;
                ushort4 o;
                o.x = f2b((acc[i][j][0] + bb.x) * qs);
                o.y = f2b((acc[i][j][1] + bb.y) * qs);
                o.z = f2b((acc[i][j][2] + bb.z) * qs);
                o.w = f2b((acc[i][j][3] + bb.w) * qs);
                *reinterpret_cast<ushort4*>(
                    &dst[((size_t)(b_ * NHH + h) * SS + s_) * HDD + d]) = o;
            }
        }
    }
}

// ---------------------------------------------------------------- flash attention
// (R4 version, best measured 76.9 us.)
// grid (64 = b*NH+h, 16 q-tiles). 256 threads, q-tile 128 (32 q per wave),
// kt tile 64 keys, double-buffered. S^T = K*Q^T with PERMUTED key rows: the QK
// C-output concatenated over a=0/1 is exactly the K=32 16x16x32 f16 PV B-operand.
// Half-tile PV carry across the per-kt barrier fills the post-barrier LDS ramp.
__global__ __launch_bounds__(256, 4) void attn_kernel(
    const unsigned short* __restrict__ Qb,
    const unsigned short* __restrict__ Kb,
    const _Float16* __restrict__ Vtb,
    const float* __restrict__ mask,
    float* __restrict__ out)
{
    __shared__ unsigned short lK[2][64 * 64];  // keys x d, swizzled (bits 0,1,3); 8 KB each
    __shared__ _Float16      lV[2][64 * 64];   // d x keys, swizzled (bits 0,1,2); 8 KB each
    __shared__ float         lmm[SS];          // mask*L2E - SH4, per key; 8 KB

    const int tid  = threadIdx.x;
    const int wave = tid >> 6, lane = tid & 63;
    const int lh   = lane & 15, quad = lane >> 4;
    const int l7   = lh & 7;
    const int bh = blockIdx.x, qt = blockIdx.y;
    const int b = bh >> 4, h = bh & 15;
    const unsigned short* Qh = Qb  + (size_t)bh * SS * HDD;
    const unsigned short* Kh = Kb  + (size_t)bh * SS * HDD;
    const _Float16*       Vh = Vtb + (size_t)bh * HDD * SS;
    const float* mk = mask + (size_t)b * SS;
    const int q0 = qt * 128;

    // Q fragments (B-operand): q = q0 + wave*32 + i*16 + lh, d = kk*32 + quad*8
    bf16x8 qF[2][2];
#pragma unroll
    for (int i = 0; i < 2; i++)
#pragma unroll
        for (int kk = 0; kk < 2; kk++)
            qF[i][kk] = *reinterpret_cast<const bf16x8*>(
                &Qh[(size_t)(q0 + wave * 32 + i * 16 + lh) * HDD + kk * 32 + quad * 8]);

    f32x4 oacc[2][4];
#pragma unroll
    for (int i = 0; i < 2; i++)
#pragma unroll
        for (int dj = 0; dj < 4; dj++) oacc[i][dj] = f32x4{0.f, 0.f, 0.f, 0.f};
    f32x4 osum[2] = {f32x4{0.f, 0.f, 0.f, 0.f}, f32x4{0.f, 0.f, 0.f, 0.f}};

    const u32x4 one_u = {0x3C003C00u, 0x3C003C00u, 0x3C003C00u, 0x3C003C00u};
    const half8 vone  = __builtin_bit_cast(half8, one_u);

    const int srow = tid >> 3;        // 0..31
    const int sg   = tid & 7;

#define STAGE(KT, BUF) do {                                                     \
    const int kb_ = (KT) * 64;                                                  \
    _Pragma("unroll")                                                           \
    for (int rr = 0; rr < 2; rr++) {                                            \
        const int row = srow + rr * 32;                                         \
        const int swk = ((sg ^ ((row & 3) | ((row >> 1) & 4))) << 3);           \
        const int swv = ((sg ^ (row & 7)) << 3);                                \
        gl_lds16(&Kh[(size_t)(kb_ + row) * HDD + swk], &lK[BUF][row * 64 + sg * 8]); \
        gl_lds16(&Vh[(size_t)row * SS + kb_ + swv],    &lV[BUF][row * 64 + sg * 8]); \
    }                                                                           \
} while (0)

// QK scores + exp2 + pack for half-tile T (0/1) of tile kt -> PF[2][4] words
#define A_HALF(T, PF) do {                                                     \
    _Pragma("unroll")                                                          \
    for (int a = 0; a < 2; a++) {                                              \
        const int key = (T) * 32 + ((lh & 12) << 1) + (a << 2) + (lh & 3);     \
        const int krow = key * 64;                                             \
        bf16x8 kf0 = *reinterpret_cast<const bf16x8*>(                         \
            &lK[buf][krow + ((quad ^ l7) << 3)]);                              \
        bf16x8 kf1 = *reinterpret_cast<const bf16x8*>(                         \
            &lK[buf][krow + (((4 + quad) ^ l7) << 3)]);                        \
        const f32x4 mm = *reinterpret_cast<const f32x4*>(                      \
            &lmm[kb + (T) * 32 + quad * 8 + a * 4]);                           \
        _Pragma("unroll")                                                      \
        for (int i = 0; i < 2; i++) {                                          \
            f32x4 s = __builtin_amdgcn_mfma_f32_16x16x32_bf16(kf0, qF[i][0], mm, 0, 0, 0); \
            s = __builtin_amdgcn_mfma_f32_16x16x32_bf16(kf1, qF[i][1], s, 0, 0, 0);        \
            PF[i][a * 2 + 0] = pkrtz_u(__builtin_amdgcn_exp2f(s[0]),           \
                                       __builtin_amdgcn_exp2f(s[1]));          \
            PF[i][a * 2 + 1] = pkrtz_u(__builtin_amdgcn_exp2f(s[2]),           \
                                       __builtin_amdgcn_exp2f(s[3]));          \
        }                                                                      \
    }                                                                          \
} while (0)

// V fragment for half-tile T of tile kt (4 conflict-free ds_read_b128)
#define LOADV(T, VF) do {                                                      \
    _Pragma("unroll")                                                          \
    for (int dj = 0; dj < 4; dj++)                                             \
        VF[dj] = *reinterpret_cast<const half8*>(                              \
            &lV[buf][(dj * 16 + lh) * 64 + ((((T) * 4 + quad) ^ l7) << 3)]);   \
} while (0)

// PV + row-sum for one half-tile: 10 pure-register K=32 f16 MFMAs
#define PV_HALF(PF, VF) do {                                                   \
    __builtin_amdgcn_s_setprio(1);                                             \
    _Pragma("unroll")                                                          \
    for (int i = 0; i < 2; i++) {                                              \
        const u32x4 pu = {PF[i][0], PF[i][1], PF[i][2], PF[i][3]};             \
        const half8 pF = __builtin_bit_cast(half8, pu);                        \
        osum[i] = __builtin_amdgcn_mfma_f32_16x16x32_f16(vone, pF, osum[i], 0, 0, 0); \
        _Pragma("unroll")                                                      \
        for (int dj = 0; dj < 4; dj++)                                         \
            oacc[i][dj] = __builtin_amdgcn_mfma_f32_16x16x32_f16(              \
                VF[dj], pF, oacc[i][dj], 0, 0, 0);                             \
    }                                                                          \
    __builtin_amdgcn_s_setprio(0);                                             \
} while (0)

    // carried half-tile state (consumed at top of body, rewritten at bottom)
    unsigned pfc[2][4];
    half8    vfc[4];
#pragma unroll
    for (int i = 0; i < 2; i++)
#pragma unroll
        for (int w = 0; w < 4; w++) pfc[i][w] = 0u;
#pragma unroll
    for (int dj = 0; dj < 4; dj++)
        vfc[dj] = __builtin_bit_cast(half8, u32x4{0u, 0u, 0u, 0u});

    STAGE(0, 0);

    // one-time: mask -> exp2-domain additive term, staged in LDS
#pragma unroll
    for (int j = 0; j < 2; j++) {
        const int idx = tid * 8 + j * 4;
        float4 m = *reinterpret_cast<const float4*>(&mk[idx]);
        float4 r;
        r.x = __builtin_fmaf(m.x, L2E, -SH4);
        r.y = __builtin_fmaf(m.y, L2E, -SH4);
        r.z = __builtin_fmaf(m.z, L2E, -SH4);
        r.w = __builtin_fmaf(m.w, L2E, -SH4);
        *reinterpret_cast<float4*>(&lmm[idx]) = r;
    }
    __syncthreads();

    for (int kt = 0; kt < SS / 64; kt++) {
        if (kt < SS / 64 - 1) STAGE(kt + 1, (kt + 1) & 1);
        const int buf = kt & 1;
        const int kb = kt * 64;

        // PV of the carried half-tile: register-only, fills post-barrier ramp
        PV_HALF(pfc, vfc);

        // half-tile 0 of this kt
        unsigned pf0[2][4];
        A_HALF(0, pf0);
        half8 vf0[4];
        LOADV(0, vf0);
        PV_HALF(pf0, vf0);

        // half-tile 1 -> carry (ds_reads complete before the barrier -> safe
        // vs STAGE(kt+2) overwriting this buffer next iteration)
        A_HALF(1, pfc);
        LOADV(1, vfc);

        if (kt < SS / 64 - 1) __syncthreads();
    }
    PV_HALF(pfc, vfc);   // last carried half-tile (kt=31, t=1)

    // finalize: osum[i][0] already holds the full row sum for q = lh (all lanes)
#pragma unroll
    for (int i = 0; i < 2; i++) {
        const float rls = 1.0f / osum[i][0];
        const int q = q0 + wave * 32 + i * 16 + lh;
#pragma unroll
        for (int dj = 0; dj < 4; dj++) {
            float4 o4;
            o4.x = oacc[i][dj][0] * rls;
            o4.y = oacc[i][dj][1] * rls;
            o4.z = oacc[i][dj][2] * rls;
            o4.w = oacc[i][dj][3] * rls;
            *reinterpret_cast<float4*>(
                &out[((size_t)b * SS + q) * HIDD + h * HDD + dj * 16 + quad * 4]) = o4;
        }
    }
#undef PV_HALF
#undef LOADV
#undef A_HALF
#undef STAGE
}

// ---------------------------------------------------------------- launch
extern "C" void kernel_launch(void* const* d_in, const int* in_sizes, int n_in,
                              void* d_out, int out_size, void* d_ws, size_t ws_size,
                              hipStream_t stream) {
    const float* x    = (const float*)d_in[0];
    const float* mask = (const float*)d_in[1];
    const float* Wq   = (const float*)d_in[2];
    const float* bq   = (const float*)d_in[3];
    const float* Wk   = (const float*)d_in[4];
    const float* bk   = (const float*)d_in[5];
    const float* Wv   = (const float*)d_in[6];
    const float* bv   = (const float*)d_in[7];
    float* out = (float*)d_out;
    (void)in_sizes; (void)n_in; (void)out_size; (void)ws_size;

    unsigned short* ws  = (unsigned short*)d_ws;
    unsigned short* xb  = ws;                                   // 8192*1024
    unsigned short* wb  = xb + (size_t)MM * HIDD;               // 3*1024*1024
    unsigned short* Qb  = wb + (size_t)3 * HIDD * HIDD;         // 8192*1024
    unsigned short* Kb  = Qb + (size_t)MM * HIDD;               // 8192*1024
    _Float16*       Vtb = (_Float16*)(Kb + (size_t)MM * HIDD);  // 8192*1024 f16, transposed

    cvt_all<<<(NX4 + 3 * NW4) / 256, 256, 0, stream>>>(x, Wq, Wk, Wv, xb, wb);

    qkv_gemm<<<dim3(MM / 128, 24), 256, 0, stream>>>(xb, wb, bq, bk, bv, Qb, Kb, Vtb);

    attn_kernel<<<dim3(BB * NHH, SS / 128), 256, 0, stream>>>(Qb, Kb, Vtb, mask, out);
}